// Round 1
// baseline (4750.403 us; speedup 1.0000x reference)
//
#include <hip/hip_runtime.h>
#include <hip/hip_bf16.h>

// ---------------- constants ----------------
#define B_      32
#define TIN_    128
#define TOUT_   500
#define R_      5
#define STEPS_  100
#define MEMD_   256
#define ATT_    256
#define DEC_    256
#define MEL_    128
#define SPEC_   513
#define SPKD_   32
#define NSTYLE_ 10

typedef unsigned short ushort_t;
typedef unsigned int   uint_t;

// ---------------- ws layout (bytes) ----------------
#define OFF_SPK     0            // 32*32 f32        (4096)
#define OFF_ACOSPK  4096         // 32*256 f32       (32768)
#define OFF_MS      36864        // 20 f32           (256)
#define OFF_KS      37120        // 20 f32           (256)
#define OFF_PREG    37376        // 100*32*512 f32   (6553600)
#define OFF_PREC    6590976      // 100*32*256 f32   (3276800)
#define OFF_Y2      9867776      // 100*32*256 f32   (3276800)
#define OFF_KEYS    13144576     // 32*128*256 bf16  (2097152)
#define OFF_ENCB    15241728     // 32*128*256 bf16  (2097152)
#define OFF_WGH     17338880     // 256*512 bf16     (262144)
#define OFF_WCH     17601024     // 256*256 bf16     (131072)
#define OFF_WQ      17732096     // 256*256 bf16     (131072)
#define OFF_WA      17863168     // 514*256 bf16     (263168)
#define OFF_WG1     18126336     // 512*512 bf16     (524288)
#define OFF_WC1     18650624     // 512*256 bf16     (262144)
#define OFF_WG2     18912768     // 512*512 bf16     (524288)
#define OFF_WC2     19437056     // 512*256 bf16     (262144)
// total ~19.7 MB

// ---------------- helpers ----------------
__device__ __forceinline__ float bflo(uint_t u){ return __uint_as_float(u << 16); }
__device__ __forceinline__ float bfhi(uint_t u){ return __uint_as_float(u & 0xffff0000u); }
__device__ __forceinline__ float bf1(ushort_t u){ return __uint_as_float(((uint_t)u) << 16); }
__device__ __forceinline__ ushort_t f2bf(float f){
    uint_t b = __float_as_uint(f);
    uint_t r = (b + 0x7fffu + ((b >> 16) & 1u)) >> 16;
    return (ushort_t)r;
}
__device__ __forceinline__ float fexp2(float x){ return __builtin_amdgcn_exp2f(x); }
__device__ __forceinline__ float frcp(float x){ return __builtin_amdgcn_rcpf(x); }
__device__ __forceinline__ float sigm_f(float x){ return frcp(1.f + fexp2(-1.44269504f * x)); }
__device__ __forceinline__ float tanh_f(float x){
    float e = fexp2(2.88539008f * x);   // e^(2x)
    return 1.f - 2.f * frcp(e + 1.f);
}

// GEMV: out[n] = sum_k x[k] * W[k][n], W bf16 row-major (K x N), 512 threads.
// Partial sums land in red[c*N + n] for c in [0, KCH). Conflict-free float4 stores.
template<int K, int N>
__device__ __forceinline__ void gemv_bf16(const ushort_t* __restrict__ W,
                                          const float* __restrict__ x,
                                          float* __restrict__ red, int tid){
    constexpr int NG  = N / 8;
    constexpr int KCH = 512 / NG;
    constexpr int KC  = K / KCH;
    static_assert(NG * 8 == N && KC * KCH == K, "bad gemv shape");
    __syncthreads();   // x ready; red free
    const int tn = tid & (NG - 1);
    const int tk = tid / NG;
    const int k0 = tk * KC;
    const uint4* Wp = reinterpret_cast<const uint4*>(W) + (size_t)k0 * (N / 8) + tn;
    float a0=0,a1=0,a2=0,a3=0,a4=0,a5=0,a6=0,a7=0;
    #pragma unroll 8
    for(int kk=0; kk<KC; ++kk){
        uint4 w = Wp[(size_t)kk * (N/8)];
        float xv = x[k0 + kk];
        a0 = fmaf(xv, bflo(w.x), a0); a1 = fmaf(xv, bfhi(w.x), a1);
        a2 = fmaf(xv, bflo(w.y), a2); a3 = fmaf(xv, bfhi(w.y), a3);
        a4 = fmaf(xv, bflo(w.z), a4); a5 = fmaf(xv, bfhi(w.z), a5);
        a6 = fmaf(xv, bflo(w.w), a6); a7 = fmaf(xv, bfhi(w.w), a7);
    }
    float4* rp = reinterpret_cast<float4*>(red) + ((tk * NG + tn) << 1);
    rp[0] = make_float4(a0,a1,a2,a3);
    rp[1] = make_float4(a4,a5,a6,a7);
    __syncthreads();
}

template<int KCH, int N>
__device__ __forceinline__ float rsum(const float* __restrict__ red, int tid){
    float t = 0.f;
    #pragma unroll
    for(int c=0;c<KCH;++c) t += red[c*N + tid];
    return t;
}

// ---------------- K1: tiny constants ----------------
__global__ __launch_bounds__(256) void k_small(
    const float* __restrict__ st, const float* __restrict__ Ws_pre,
    const float* __restrict__ bs_pre, const float* __restrict__ Wk_s,
    const float* __restrict__ spk_embed, const int* __restrict__ speaker,
    const float* __restrict__ Wa, const float* __restrict__ ba,
    float* __restrict__ spk_sel, float* __restrict__ aco_spk,
    float* __restrict__ ms_g, float* __restrict__ ks_g)
{
    __shared__ float spk_l[B_*SPKD_];
    __shared__ float ms_l[NSTYLE_*2];
    const int tid = threadIdx.x;
    for(int i=tid; i<B_*SPKD_; i+=256){
        int b = i >> 5, j = i & 31;
        float v = spk_embed[speaker[b]*SPKD_ + j];
        spk_l[i] = v; spk_sel[i] = v;
    }
    if(tid < NSTYLE_*2){
        int n = tid >> 1, j = tid & 1;
        float v = st[n*2]*Ws_pre[j] + st[n*2+1]*Ws_pre[2+j] + bs_pre[j];
        v = fmaxf(v, 0.f);
        ms_l[tid] = v; ms_g[tid] = v;
    }
    __syncthreads();
    if(tid < NSTYLE_*2){
        int n = tid >> 1, j = tid & 1;
        ks_g[tid] = ms_l[n*2]*Wk_s[j] + ms_l[n*2+1]*Wk_s[2+j];
    }
    for(int i=tid; i<B_*DEC_; i+=256){
        int b = i >> 8, n = i & 255;
        float acc = ba[n];
        #pragma unroll
        for(int k=0;k<SPKD_;++k) acc = fmaf(spk_l[b*SPKD_+k], Wa[(256+k)*256 + n], acc);
        aco_spk[i] = acc;
    }
}

// ---------------- K2: f32 -> bf16 conversions ----------------
struct Segs { const float* src[10]; ushort_t* dst[10]; int n[10]; };
__global__ __launch_bounds__(256) void k_convert(Segs sg){
    const int seg = blockIdx.y;
    const int n = sg.n[seg];
    const float* s = sg.src[seg];
    ushort_t* d = sg.dst[seg];
    for(int i = blockIdx.x*256 + threadIdx.x; i < n; i += gridDim.x*256)
        d[i] = f2bf(s[i]);
}

// ---------------- K4: keys = enc @ Wk -> bf16 ----------------
__global__ __launch_bounds__(256) void k_keys(const float* __restrict__ enc,
                                              const float* __restrict__ Wk,
                                              ushort_t* __restrict__ keysb){
    __shared__ float x16[16][256];
    const int bid = blockIdx.x;      // 256 = 32 b * 8 tgroups
    const int b = bid >> 3, tg = bid & 7, t0 = tg*16;
    const int tid = threadIdx.x;
    for(int i=tid; i<16*256; i+=256){
        int r = i >> 8, k = i & 255;
        x16[r][k] = enc[((size_t)b*TIN_ + t0 + r)*MEMD_ + k];
    }
    __syncthreads();
    float acc[16];
    #pragma unroll
    for(int r=0;r<16;++r) acc[r] = 0.f;
    for(int k=0;k<256;++k){
        float w = Wk[k*256 + tid];
        #pragma unroll
        for(int r=0;r<16;++r) acc[r] = fmaf(x16[r][k], w, acc[r]);
    }
    #pragma unroll
    for(int r=0;r<16;++r) keysb[((size_t)b*TIN_ + t0 + r)*ATT_ + tid] = f2bf(acc[r]);
}

// ---------------- K3: prenet + x-part of att-GRU for all steps ----------------
__global__ __launch_bounds__(256) void k_prenet(
    const float* __restrict__ mg, const float* __restrict__ spk_sel,
    const float* __restrict__ Wp1, const float* __restrict__ bp1,
    const float* __restrict__ Wp2, const float* __restrict__ bp2,
    const float* __restrict__ Wg_att, const float* __restrict__ bg_att,
    const float* __restrict__ Wc_att, const float* __restrict__ bc_att,
    float* __restrict__ preg, float* __restrict__ prec)
{
    __shared__ float fr[16][128];
    __shared__ float p1[16][256];
    __shared__ float p2[16][128];
    __shared__ float spk_l[16][32];
    const int r0 = blockIdx.x * 16;     // 200 blocks * 16 rows = 3200 (s*32+b)
    const int tid = threadIdx.x;
    for(int i=tid; i<16*128; i+=256){
        int r = i >> 7, m = i & 127;
        int row = r0 + r, s = row >> 5, b = row & 31;
        fr[r][m] = (s == 0) ? 0.f : mg[((size_t)b*TOUT_ + s*R_ - 1)*MEL_ + m];
    }
    for(int i=tid; i<16*32; i+=256){
        int r = i >> 5, j = i & 31;
        spk_l[r][j] = spk_sel[((r0 + r) & 31)*SPKD_ + j];
    }
    __syncthreads();
    { // p1 = relu(fr @ Wp1 + bp1), N=256
        float acc[16];
        #pragma unroll
        for(int r=0;r<16;++r) acc[r]=0.f;
        for(int k=0;k<128;++k){
            float w = Wp1[k*256 + tid];
            #pragma unroll
            for(int r=0;r<16;++r) acc[r] = fmaf(fr[r][k], w, acc[r]);
        }
        float bb = bp1[tid];
        #pragma unroll
        for(int r=0;r<16;++r) p1[r][tid] = fmaxf(acc[r] + bb, 0.f);
    }
    __syncthreads();
    if(tid < 128){ // p2 = relu(p1 @ Wp2 + bp2), N=128
        float acc[16];
        #pragma unroll
        for(int r=0;r<16;++r) acc[r]=0.f;
        for(int k=0;k<256;++k){
            float w = Wp2[k*128 + tid];
            #pragma unroll
            for(int r=0;r<16;++r) acc[r] = fmaf(p1[r][k], w, acc[r]);
        }
        float bb = bp2[tid];
        #pragma unroll
        for(int r=0;r<16;++r) p2[r][tid] = fmaxf(acc[r] + bb, 0.f);
    }
    __syncthreads();
    { // preg = [p2, spk] @ Wg_att[0:160] + bg_att  (N=512: o=tid, tid+256)
        float aA[16], aB[16];
        #pragma unroll
        for(int r=0;r<16;++r){ aA[r]=0.f; aB[r]=0.f; }
        for(int k=0;k<128;++k){
            float wA = Wg_att[k*512 + tid], wB = Wg_att[k*512 + tid + 256];
            #pragma unroll
            for(int r=0;r<16;++r){ float pv = p2[r][k]; aA[r]=fmaf(pv,wA,aA[r]); aB[r]=fmaf(pv,wB,aB[r]); }
        }
        for(int k=0;k<32;++k){
            float wA = Wg_att[(128+k)*512 + tid], wB = Wg_att[(128+k)*512 + tid + 256];
            #pragma unroll
            for(int r=0;r<16;++r){ float sv = spk_l[r][k]; aA[r]=fmaf(sv,wA,aA[r]); aB[r]=fmaf(sv,wB,aB[r]); }
        }
        float bA = bg_att[tid], bB = bg_att[tid + 256];
        #pragma unroll
        for(int r=0;r<16;++r){
            preg[(size_t)(r0+r)*512 + tid]       = aA[r] + bA;
            preg[(size_t)(r0+r)*512 + tid + 256] = aB[r] + bB;
        }
    }
    { // prec = [p2, spk] @ Wc_att[0:160] + bc_att  (N=256)
        float acc[16];
        #pragma unroll
        for(int r=0;r<16;++r) acc[r]=0.f;
        for(int k=0;k<128;++k){
            float w = Wc_att[k*256 + tid];
            #pragma unroll
            for(int r=0;r<16;++r) acc[r] = fmaf(p2[r][k], w, acc[r]);
        }
        for(int k=0;k<32;++k){
            float w = Wc_att[(128+k)*256 + tid];
            #pragma unroll
            for(int r=0;r<16;++r) acc[r] = fmaf(spk_l[r][k], w, acc[r]);
        }
        float bb = bc_att[tid];
        #pragma unroll
        for(int r=0;r<16;++r) prec[(size_t)(r0+r)*256 + tid] = acc[r] + bb;
    }
}

// ---------------- K5: the sequential scan, one WG per batch row ----------------
__global__ __launch_bounds__(512) void k_scan(
    const float* __restrict__ preg, const float* __restrict__ prec,
    const ushort_t* __restrict__ keysb_all, const ushort_t* __restrict__ encb_all,
    const ushort_t* __restrict__ Wgh, const ushort_t* __restrict__ Wch,
    const ushort_t* __restrict__ Wqb, const ushort_t* __restrict__ Wab,
    const ushort_t* __restrict__ Wg1b, const ushort_t* __restrict__ Wc1b,
    const ushort_t* __restrict__ Wg2b, const ushort_t* __restrict__ Wc2b,
    const float* __restrict__ acospk, const float* __restrict__ vatt,
    const float* __restrict__ bg1, const float* __restrict__ bc1,
    const float* __restrict__ bg2, const float* __restrict__ bc2,
    const float* __restrict__ ms, const float* __restrict__ ks,
    const float* __restrict__ vs, const float* __restrict__ wqs,
    const int* __restrict__ inp_mask,
    float* __restrict__ y2g, float* __restrict__ out_alpha)
{
    const int b = blockIdx.x, tid = threadIdx.x;
    __shared__ float h_att[256], h1[256], h2[256];
    __shared__ float xb[512], g[512];
    __shared__ float aco[256], ctx[256], y1s[256], qWl[256];
    __shared__ float alpha[128], ebuf[128];
    __shared__ __align__(16) float red[4096];
    __shared__ float acospk_l[256], vatt_l[256];
    __shared__ float bg1_l[512], bc1_l[256], bg2_l[512], bc2_l[256], wqs_l[512];
    __shared__ float ms_l[20], ks_l[20], qws_l[2], ctxs_l[2], sm[2];

    if(tid < 256){
        h_att[tid]=0.f; h1[tid]=0.f; h2[tid]=0.f;
        acospk_l[tid]=acospk[b*256+tid]; vatt_l[tid]=vatt[tid];
        bc1_l[tid]=bc1[tid]; bc2_l[tid]=bc2[tid];
    }
    bg1_l[tid]=bg1[tid]; bg2_l[tid]=bg2[tid]; wqs_l[tid]=wqs[tid];
    if(tid < 20){ ms_l[tid]=ms[tid]; ks_l[tid]=ks[tid]; }
    const int maskb = inp_mask[b];
    const float vs0 = vs[0], vs1 = vs[1];
    const ushort_t* keysb = keysb_all + (size_t)b*TIN_*ATT_;
    const ushort_t* encb  = encb_all  + (size_t)b*TIN_*MEMD_;
    __syncthreads();

    for(int s=0; s<STEPS_; ++s){
        const int base = s*B_ + b;
        // ---- A: att-GRU gates = sigmoid(pre_g + h_att @ Wgh) ----
        gemv_bf16<256,512>(Wgh, h_att, red, tid);
        { float v = preg[(size_t)base*512 + tid] + rsum<8,512>(red, tid); g[tid] = sigm_f(v); }
        if(tid < 256) xb[tid] = g[tid] * h_att[tid];           // r*h
        // ---- B: candidate + h_att update ----
        gemv_bf16<256,256>(Wch, xb, red, tid);
        if(tid < 256){
            float c = tanh_f(prec[(size_t)base*256 + tid] + rsum<16,256>(red, tid));
            float u = g[256 + tid];
            h_att[tid] = u*h_att[tid] + (1.f - u)*c;
        }
        // ---- C: qW = h_att @ Wq ----
        gemv_bf16<256,256>(Wqb, h_att, red, tid);
        if(tid < 256) qWl[tid] = rsum<16,256>(red, tid);
        // style query (wave 0)
        if(tid < 64){
            float a0=0.f, a1=0.f;
            #pragma unroll
            for(int i=0;i<4;++i){
                int k = tid*4 + i; float hv = h_att[k];
                a0 = fmaf(hv, wqs_l[k*2],   a0);
                a1 = fmaf(hv, wqs_l[k*2+1], a1);
            }
            #pragma unroll
            for(int d=1; d<64; d<<=1){ a0 += __shfl_xor(a0,d,64); a1 += __shfl_xor(a1,d,64); }
            if(tid == 0){ qws_l[0]=a0; qws_l[1]=a1; }
        }
        // ---- D: attention scores + masked softmax ----
        __syncthreads();     // red reuse guard
        {
            const int tt = tid & 127, tc = tid >> 7;    // 128 t x 4 chunks of 64 a
            const uint4* kp = reinterpret_cast<const uint4*>(keysb + (size_t)tt*ATT_ + tc*64);
            float p = 0.f;
            #pragma unroll
            for(int i=0;i<8;++i){
                uint4 w = kp[i];
                int a = tc*64 + i*8;
                p = fmaf(vatt_l[a+0], tanh_f(bflo(w.x)+qWl[a+0]), p);
                p = fmaf(vatt_l[a+1], tanh_f(bfhi(w.x)+qWl[a+1]), p);
                p = fmaf(vatt_l[a+2], tanh_f(bflo(w.y)+qWl[a+2]), p);
                p = fmaf(vatt_l[a+3], tanh_f(bfhi(w.y)+qWl[a+3]), p);
                p = fmaf(vatt_l[a+4], tanh_f(bflo(w.z)+qWl[a+4]), p);
                p = fmaf(vatt_l[a+5], tanh_f(bfhi(w.z)+qWl[a+5]), p);
                p = fmaf(vatt_l[a+6], tanh_f(bflo(w.w)+qWl[a+6]), p);
                p = fmaf(vatt_l[a+7], tanh_f(bfhi(w.w)+qWl[a+7]), p);
            }
            red[tc*128 + tt] = p;
        }
        __syncthreads();
        if(tid < 128){
            float e = red[tid] + red[128+tid] + red[256+tid] + red[384+tid];
            ebuf[tid] = (tid < maskb) ? e : -1e9f;
        }
        __syncthreads();
        if(tid < 64){
            float m = fmaxf(ebuf[tid], ebuf[tid+64]);
            #pragma unroll
            for(int d=1; d<64; d<<=1) m = fmaxf(m, __shfl_xor(m,d,64));
            if(tid == 0) sm[0] = m;
        }
        __syncthreads();
        if(tid < 128) alpha[tid] = fexp2((ebuf[tid] - sm[0]) * 1.44269504f);
        __syncthreads();
        if(tid < 64){
            float ssv = alpha[tid] + alpha[tid+64];
            #pragma unroll
            for(int d=1; d<64; d<<=1) ssv += __shfl_xor(ssv,d,64);
            if(tid == 0) sm[1] = frcp(ssv);
        }
        __syncthreads();
        if(tid < 128){
            float a = alpha[tid] * sm[1];
            alpha[tid] = a;
            out_alpha[(size_t)b*STEPS_*TIN_ + s*TIN_ + tid] = a;
        }
        // ---- E: context = alpha @ enc[b] ----
        gemv_bf16<128,256>(encb, alpha, red, tid);
        if(tid < 256) ctx[tid] = rsum<16,256>(red, tid);
        // ---- F: style softmax (thread 0; tiny) ----
        if(tid == 0){
            float q0 = qws_l[0], q1 = qws_l[1];
            float es[NSTYLE_]; float m = -1e30f;
            #pragma unroll
            for(int n=0;n<NSTYLE_;++n){
                float t = vs0*tanh_f(ks_l[n*2]+q0) + vs1*tanh_f(ks_l[n*2+1]+q1);
                es[n]=t; m=fmaxf(m,t);
            }
            float ssv = 0.f;
            #pragma unroll
            for(int n=0;n<NSTYLE_;++n){ float p=fexp2((es[n]-m)*1.44269504f); es[n]=p; ssv+=p; }
            float inv = frcp(ssv); float c0=0.f, c1=0.f;
            #pragma unroll
            for(int n=0;n<NSTYLE_;++n){ float a=es[n]*inv; c0=fmaf(a,ms_l[n*2],c0); c1=fmaf(a,ms_l[n*2+1],c1); }
            ctxs_l[0]=c0; ctxs_l[1]=c1;
        }
        if(tid < 256){ xb[tid]=h_att[tid]; xb[256+tid]=ctx[tid]; }
        // ---- G: aco = acospk + [h_att, ctx] @ Wa_used + ctxs @ Wa_s ----
        gemv_bf16<512,256>(Wab, xb, red, tid);
        if(tid < 256){
            float v = acospk_l[tid] + rsum<16,256>(red, tid);
            v = fmaf(ctxs_l[0], bf1(Wab[512*256 + tid]), v);
            v = fmaf(ctxs_l[1], bf1(Wab[513*256 + tid]), v);
            aco[tid]=v; xb[tid]=v; xb[256+tid]=h1[tid];
        }
        // ---- H: GRU1 gates ----
        gemv_bf16<512,512>(Wg1b, xb, red, tid);
        { g[tid] = sigm_f(rsum<8,512>(red, tid) + bg1_l[tid]); }
        if(tid < 256) xb[256+tid] = g[tid]*h1[tid];
        // ---- I: GRU1 candidate + y1 ----
        gemv_bf16<512,256>(Wc1b, xb, red, tid);
        if(tid < 256){
            float c = tanh_f(rsum<16,256>(red, tid) + bc1_l[tid]);
            float u = g[256+tid];
            float hn = u*h1[tid] + (1.f-u)*c;
            h1[tid] = hn;
            float y = hn + aco[tid];
            y1s[tid] = y; xb[tid] = y; xb[256+tid] = h2[tid];
        }
        // ---- J: GRU2 gates ----
        gemv_bf16<512,512>(Wg2b, xb, red, tid);
        { g[tid] = sigm_f(rsum<8,512>(red, tid) + bg2_l[tid]); }
        if(tid < 256) xb[256+tid] = g[tid]*h2[tid];
        // ---- K: GRU2 candidate + y2 ----
        gemv_bf16<512,256>(Wc2b, xb, red, tid);
        if(tid < 256){
            float c = tanh_f(rsum<16,256>(red, tid) + bc2_l[tid]);
            float u = g[256+tid];
            float hn = u*h2[tid] + (1.f-u)*c;
            h2[tid] = hn;
            y2g[(size_t)base*256 + tid] = hn + y1s[tid];
        }
    }
}

// ---------------- K6: output_mel = y2 @ Wo + bo (with (s,b,r)->(b,t) scatter) ----------------
__global__ __launch_bounds__(256) void k_omel(const float* __restrict__ y2g,
                                              const float* __restrict__ Wo,
                                              const float* __restrict__ bo,
                                              float* __restrict__ out_mel){
    __shared__ float y8[8][256];
    const int r0 = blockIdx.x * 8;   // 400 blocks * 8 rows = 3200
    const int tid = threadIdx.x;
    for(int i=tid; i<8*256; i+=256){ int r=i>>8, k=i&255; y8[r][k] = y2g[(size_t)(r0+r)*256 + k]; }
    __syncthreads();
    float aA[8], aB[8], aC[8];
    #pragma unroll
    for(int r=0;r<8;++r){ aA[r]=0.f; aB[r]=0.f; aC[r]=0.f; }
    for(int k=0;k<256;++k){
        float wA = Wo[(size_t)k*640 + tid];
        float wB = Wo[(size_t)k*640 + tid + 256];
        float wC = (tid < 128) ? Wo[(size_t)k*640 + tid + 512] : 0.f;
        #pragma unroll
        for(int r=0;r<8;++r){
            float yv = y8[r][k];
            aA[r]=fmaf(yv,wA,aA[r]); aB[r]=fmaf(yv,wB,aB[r]); aC[r]=fmaf(yv,wC,aC[r]);
        }
    }
    float bA = bo[tid], bB = bo[tid+256], bC = (tid<128)? bo[tid+512] : 0.f;
    #pragma unroll
    for(int r=0;r<8;++r){
        int row = r0 + r, s = row >> 5, b = row & 31;
        int m = tid & 127;
        out_mel[((size_t)b*TOUT_ + s*R_ + (tid>>7))*MEL_ + m]       = aA[r] + bA;
        out_mel[((size_t)b*TOUT_ + s*R_ + 2 + (tid>>7))*MEL_ + m]   = aB[r] + bB;
        if(tid < 128)
            out_mel[((size_t)b*TOUT_ + s*R_ + 4)*MEL_ + tid]        = aC[r] + bC;
    }
}

// ---------------- K7: output_spec = mel @ Wspec + bspec ----------------
__global__ __launch_bounds__(256) void k_spec(const float* __restrict__ out_mel,
                                              const float* __restrict__ Wspec,
                                              const float* __restrict__ bspec,
                                              float* __restrict__ out_spec){
    __shared__ float m8[8][128];
    const int r0 = blockIdx.x * 8;   // 2000 blocks * 8 rows = 16000 = 32*500
    const int tid = threadIdx.x;
    for(int i=tid; i<8*128; i+=256){ int r=i>>7, k=i&127; m8[r][k] = out_mel[(size_t)(r0+r)*128 + k]; }
    __syncthreads();
    float aA[8], aB[8], aC[8];
    #pragma unroll
    for(int r=0;r<8;++r){ aA[r]=0.f; aB[r]=0.f; aC[r]=0.f; }
    for(int k=0;k<128;++k){
        float wA = Wspec[(size_t)k*SPEC_ + tid];
        float wB = Wspec[(size_t)k*SPEC_ + 256 + tid];
        float wC = (tid == 0) ? Wspec[(size_t)k*SPEC_ + 512] : 0.f;
        #pragma unroll
        for(int r=0;r<8;++r){
            float mv = m8[r][k];
            aA[r]=fmaf(mv,wA,aA[r]); aB[r]=fmaf(mv,wB,aB[r]); aC[r]=fmaf(mv,wC,aC[r]);
        }
    }
    float bA = bspec[tid], bB = bspec[256+tid];
    #pragma unroll
    for(int r=0;r<8;++r){
        size_t row = (size_t)(r0 + r);
        out_spec[row*SPEC_ + tid]       = aA[r] + bA;
        out_spec[row*SPEC_ + 256 + tid] = aB[r] + bB;
        if(tid == 0) out_spec[row*SPEC_ + 512] = aC[r] + bspec[512];
    }
}

// ---------------- launcher ----------------
extern "C" void kernel_launch(void* const* d_in, const int* in_sizes, int n_in,
                              void* d_out, int out_size, void* d_ws, size_t ws_size,
                              hipStream_t stream) {
    const float* enc       = (const float*)d_in[0];
    const float* st        = (const float*)d_in[1];
    const float* mg        = (const float*)d_in[2];
    const int*   speaker   = (const int*)  d_in[3];
    const int*   inp_mask  = (const int*)  d_in[4];
    const float* spk_embed = (const float*)d_in[5];
    const float* Wp1=(const float*)d_in[6],  *bp1=(const float*)d_in[7];
    const float* Wp2=(const float*)d_in[8],  *bp2=(const float*)d_in[9];
    const float* Wg_att=(const float*)d_in[10], *bg_att=(const float*)d_in[11];
    const float* Wc_att=(const float*)d_in[12], *bc_att=(const float*)d_in[13];
    const float* Wk=(const float*)d_in[14], *Wq=(const float*)d_in[15], *v_att=(const float*)d_in[16];
    const float* Ws_pre=(const float*)d_in[17], *bs_pre=(const float*)d_in[18];
    const float* Wk_s=(const float*)d_in[19], *Wq_s=(const float*)d_in[20], *v_s=(const float*)d_in[21];
    const float* Wa=(const float*)d_in[22], *ba=(const float*)d_in[23];
    const float* Wg1=(const float*)d_in[24], *bg1=(const float*)d_in[25];
    const float* Wc1=(const float*)d_in[26], *bc1=(const float*)d_in[27];
    const float* Wg2=(const float*)d_in[28], *bg2=(const float*)d_in[29];
    const float* Wc2=(const float*)d_in[30], *bc2=(const float*)d_in[31];
    const float* Wo=(const float*)d_in[32], *bo=(const float*)d_in[33];
    const float* Wspec=(const float*)d_in[34], *bspec=(const float*)d_in[35];

    float* out       = (float*)d_out;
    float* out_mel   = out;                       // 32*500*128 = 2,048,000
    float* out_spec  = out + 2048000;             // 32*500*513 = 8,208,000
    float* out_alpha = out + 10256000;            // 32*100*128 =   409,600

    char* ws = (char*)d_ws;
    float*    spk_sel = (float*)(ws + OFF_SPK);
    float*    aco_spk = (float*)(ws + OFF_ACOSPK);
    float*    ms_g    = (float*)(ws + OFF_MS);
    float*    ks_g    = (float*)(ws + OFF_KS);
    float*    preg    = (float*)(ws + OFF_PREG);
    float*    prec    = (float*)(ws + OFF_PREC);
    float*    y2g     = (float*)(ws + OFF_Y2);
    ushort_t* keysb   = (ushort_t*)(ws + OFF_KEYS);
    ushort_t* encb    = (ushort_t*)(ws + OFF_ENCB);
    ushort_t* wgh     = (ushort_t*)(ws + OFF_WGH);
    ushort_t* wch     = (ushort_t*)(ws + OFF_WCH);
    ushort_t* wqb     = (ushort_t*)(ws + OFF_WQ);
    ushort_t* wab     = (ushort_t*)(ws + OFF_WA);
    ushort_t* wg1b    = (ushort_t*)(ws + OFF_WG1);
    ushort_t* wc1b    = (ushort_t*)(ws + OFF_WC1);
    ushort_t* wg2b    = (ushort_t*)(ws + OFF_WG2);
    ushort_t* wc2b    = (ushort_t*)(ws + OFF_WC2);

    k_small<<<dim3(1), dim3(256), 0, stream>>>(st, Ws_pre, bs_pre, Wk_s, spk_embed,
                                               speaker, Wa, ba, spk_sel, aco_spk, ms_g, ks_g);

    Segs sg;
    sg.src[0]=Wg_att + 160*512; sg.dst[0]=wgh;          sg.n[0]=256*512;
    sg.src[1]=Wc_att + 160*256; sg.dst[1]=wch;          sg.n[1]=256*256;
    sg.src[2]=Wq;               sg.dst[2]=wqb;          sg.n[2]=256*256;
    sg.src[3]=Wa;               sg.dst[3]=wab;          sg.n[3]=256*256;
    sg.src[4]=Wa + 288*256;     sg.dst[4]=wab + 65536;  sg.n[4]=258*256;
    sg.src[5]=Wg1;              sg.dst[5]=wg1b;         sg.n[5]=512*512;
    sg.src[6]=Wc1;              sg.dst[6]=wc1b;         sg.n[6]=512*256;
    sg.src[7]=Wg2;              sg.dst[7]=wg2b;         sg.n[7]=512*512;
    sg.src[8]=Wc2;              sg.dst[8]=wc2b;         sg.n[8]=512*256;
    sg.src[9]=enc;              sg.dst[9]=encb;         sg.n[9]=32*128*256;
    k_convert<<<dim3(512,10), dim3(256), 0, stream>>>(sg);

    k_keys  <<<dim3(256),  dim3(256), 0, stream>>>(enc, Wk, keysb);
    k_prenet<<<dim3(200),  dim3(256), 0, stream>>>(mg, spk_sel, Wp1, bp1, Wp2, bp2,
                                                   Wg_att, bg_att, Wc_att, bc_att, preg, prec);
    k_scan  <<<dim3(32),   dim3(512), 0, stream>>>(preg, prec, keysb, encb,
                                                   wgh, wch, wqb, wab, wg1b, wc1b, wg2b, wc2b,
                                                   aco_spk, v_att, bg1, bc1, bg2, bc2,
                                                   ms_g, ks_g, v_s, Wq_s, inp_mask,
                                                   y2g, out_alpha);
    k_omel  <<<dim3(400),  dim3(256), 0, stream>>>(y2g, Wo, bo, out_mel);
    k_spec  <<<dim3(2000), dim3(256), 0, stream>>>(out_mel, Wspec, bspec, out_spec);
}